// Round 23
// baseline (479.518 us; speedup 1.0000x reference)
//
#include <hip/hip_runtime.h>
#include <hip/hip_bf16.h>
#include <cstddef>

#define NN 50000
#define NE 800000
#define NPAD 50176
#define SCAN_BLOCKS 196   // ceil(NN/256)
#define BN_EPS 1e-5f
#define EB 256            // edges per block in edge MLP (4 waves); NE % EB == 0
#define BN_GRID 2048
#define BN_REPS 8

typedef __bf16 bf16x8f __attribute__((ext_vector_type(8)));
typedef unsigned short u16x8 __attribute__((ext_vector_type(8)));
typedef float f32x4 __attribute__((ext_vector_type(4)));

__device__ __forceinline__ unsigned short f2bf(float f) {
    __hip_bfloat16 h = __float2bfloat16(f);
    return *reinterpret_cast<unsigned short*>(&h);
}
__device__ __forceinline__ float bf2f(unsigned short u) {
    return __uint_as_float(((unsigned int)u) << 16);
}

// ---------------- CSR build ----------------
__global__ __launch_bounds__(256) void k_count_int(const int* __restrict__ dst,
                                                   int* __restrict__ cnt) {
    int e = blockIdx.x * 256 + threadIdx.x;
    if (e < NE) atomicAdd(&cnt[dst[e]], 1);
}

__global__ __launch_bounds__(256) void k_bsum(const int* __restrict__ cnt,
                                              int* __restrict__ bsum) {
    __shared__ int red[4];
    int i = blockIdx.x * 256 + threadIdx.x;
    int v = (i < NN) ? cnt[i] : 0;
    #pragma unroll
    for (int off = 32; off > 0; off >>= 1) v += __shfl_down(v, off, 64);
    int lane = threadIdx.x & 63, w = threadIdx.x >> 6;
    if (lane == 0) red[w] = v;
    __syncthreads();
    if (threadIdx.x == 0) bsum[blockIdx.x] = red[0] + red[1] + red[2] + red[3];
}

// per-block exclusive scan; block base computed from raw bsum
__global__ __launch_bounds__(256) void k_scan_fin(const int* __restrict__ cnt,
                                                  const int* __restrict__ bsum,
                                                  int* __restrict__ row_start,
                                                  int* __restrict__ cursor,
                                                  float* __restrict__ dsq) {
    __shared__ int tmp[256];
    __shared__ int red[4];
    const int t = threadIdx.x;

    int pv = (t < blockIdx.x) ? bsum[t] : 0;   // blockIdx.x < 256
    #pragma unroll
    for (int off = 32; off > 0; off >>= 1) pv += __shfl_down(pv, off, 64);
    if ((t & 63) == 0) red[t >> 6] = pv;
    __syncthreads();
    const int blockbase = red[0] + red[1] + red[2] + red[3];

    int i = blockIdx.x * 256 + t;
    int c = (i < NN) ? cnt[i] : 0;
    tmp[t] = c;
    __syncthreads();
    #pragma unroll
    for (int off = 1; off < 256; off <<= 1) {
        int u = (t >= off) ? tmp[t - off] : 0;
        __syncthreads();
        tmp[t] += u;
        __syncthreads();
    }
    int excl = tmp[t] - c + blockbase;
    if (i < NN) {
        row_start[i] = excl;
        cursor[i] = excl;
        dsq[i] = rsqrtf((float)c + 1.0f);
    }
    if (i == 0) row_start[NN] = NE;
}

// fill compact CSR entries: src as ushort (NN < 65536)
__global__ __launch_bounds__(256) void k_fill(const int* __restrict__ src,
                                              const int* __restrict__ dst,
                                              int* __restrict__ cursor,
                                              unsigned short* __restrict__ pk2) {
    int e = blockIdx.x * 256 + threadIdx.x;
    if (e < NE) {
        int pos = atomicAdd(&cursor[dst[e]], 1);
        pk2[pos] = (unsigned short)src[e];
    }
}

// ---------------- MFMA bf16 GEMM ----------------
// ABF: A is bf16 (ushort). BNA: fused BN+relu on A; `sums` holds BN_REPS replicas of
// raw [s(K)][ss(K)] (stride 2K each); each block derives mean/invstd into LDS.
// SCALE: out *= dsq[row]. FUSEB: B is We1[128][64]; fused N=128 output.
template <int BNT, bool BNA, bool SCALE, bool ABF, bool FUSEB>
__global__ __launch_bounds__(256) void k_gemm_mfma(const float* __restrict__ A,
                                                   const unsigned short* __restrict__ Ab,
                                                   const float* __restrict__ B,
                                                   unsigned short* __restrict__ Cb,
                                                   int M, int K, int N,
                                                   const float* __restrict__ sums,
                                                   const float* __restrict__ g,
                                                   const float* __restrict__ be,
                                                   const float* __restrict__ dsq) {
    __shared__ unsigned short As[128 * 56];
    __shared__ unsigned short Bs[BNT * 56];
    __shared__ float bn_mean[256];
    __shared__ float bn_istd[256];
    const int tid = threadIdx.x;
    const int lane = tid & 63, wave = tid >> 6;
    const int row0 = blockIdx.y * 128, col0 = blockIdx.x * BNT;
    constexpr int NCT = BNT / 16;

    if constexpr (BNA) {
        if (tid < K) {
            float s = 0.0f, ss = 0.0f;
            #pragma unroll
            for (int rep = 0; rep < BN_REPS; ++rep) {
                s += sums[rep * 2 * K + tid];
                ss += sums[rep * 2 * K + K + tid];
            }
            const float invN = 1.0f / (float)NN;
            float mean = s * invN;
            float var = ss * invN - mean * mean;
            bn_mean[tid] = mean;
            bn_istd[tid] = rsqrtf(var + BN_EPS);
        }
        __syncthreads();
    }

    f32x4 acc[2][NCT] = {};

    const int r16 = lane & 15;
    const int kg = (lane >> 4) * 8;

    for (int k0 = 0; k0 < K; k0 += 32) {
        // ---- stage A: 128 rows x 32 k ----
        {
            int row = tid >> 1;
            int kh = (tid & 1) * 16;
            int gr = row0 + row;
            unsigned short* dp = &As[row * 56 + kh];
            if constexpr (!ABF) {
                unsigned short tmp[16];
                if (gr < M) {
                    const float* ap = A + (size_t)gr * K + k0 + kh;
                    #pragma unroll
                    for (int j = 0; j < 16; ++j) {
                        float v = ap[j];
                        if constexpr (BNA) {
                            int c = k0 + kh + j;
                            v = fmaxf((v - bn_mean[c]) * bn_istd[c] * g[c] + be[c], 0.0f);
                        }
                        tmp[j] = f2bf(v);
                    }
                } else {
                    #pragma unroll
                    for (int j = 0; j < 16; ++j) tmp[j] = 0;
                }
                *reinterpret_cast<u16x8*>(dp) = *reinterpret_cast<const u16x8*>(&tmp[0]);
                *reinterpret_cast<u16x8*>(dp + 8) = *reinterpret_cast<const u16x8*>(&tmp[8]);
            } else {
                u16x8 t0 = {}, t1 = {};
                if (gr < M) {
                    const unsigned short* ap = Ab + (size_t)gr * K + k0 + kh;
                    t0 = *reinterpret_cast<const u16x8*>(ap);
                    t1 = *reinterpret_cast<const u16x8*>(ap + 8);
                    if constexpr (BNA) {
                        #pragma unroll
                        for (int j = 0; j < 8; ++j) {
                            int c0 = k0 + kh + j, c1 = k0 + kh + 8 + j;
                            float v0 = fmaxf((bf2f(t0[j]) - bn_mean[c0]) * bn_istd[c0] * g[c0] + be[c0], 0.0f);
                            float v1 = fmaxf((bf2f(t1[j]) - bn_mean[c1]) * bn_istd[c1] * g[c1] + be[c1], 0.0f);
                            t0[j] = f2bf(v0);
                            t1[j] = f2bf(v1);
                        }
                    }
                }
                *reinterpret_cast<u16x8*>(dp) = t0;
                *reinterpret_cast<u16x8*>(dp + 8) = t1;
            }
        }
        // ---- stage B transposed: Bs[col][k] ----
        {
            constexpr int JC = (BNT == 128) ? 16 : 8;
            int col = tid & (BNT - 1);
            int kh = (tid / BNT) * JC;
            unsigned short tmp[JC];
            #pragma unroll
            for (int j = 0; j < JC; ++j) {
                float bv;
                if constexpr (FUSEB) {
                    int kk = k0 + kh + j;
                    int c = col0 + col;
                    bv = (c < 64) ? B[(size_t)kk * 64 + c]
                                  : B[(size_t)(64 + kk) * 64 + (c - 64)];
                } else {
                    bv = B[(size_t)(k0 + kh + j) * N + col0 + col];
                }
                tmp[j] = f2bf(bv);
            }
            unsigned short* dp = &Bs[col * 56 + kh];
            #pragma unroll
            for (int j = 0; j < JC; j += 8)
                *reinterpret_cast<u16x8*>(dp + j) = *reinterpret_cast<const u16x8*>(&tmp[j]);
        }
        __syncthreads();

        bf16x8f af[2];
        bf16x8f bfr[NCT];
        #pragma unroll
        for (int rt = 0; rt < 2; ++rt)
            af[rt] = __builtin_bit_cast(bf16x8f,
                *reinterpret_cast<const u16x8*>(&As[(wave * 32 + rt * 16 + r16) * 56 + kg]));
        #pragma unroll
        for (int ct = 0; ct < NCT; ++ct)
            bfr[ct] = __builtin_bit_cast(bf16x8f,
                *reinterpret_cast<const u16x8*>(&Bs[(ct * 16 + r16) * 56 + kg]));
        #pragma unroll
        for (int rt = 0; rt < 2; ++rt)
            #pragma unroll
            for (int ct = 0; ct < NCT; ++ct)
                acc[rt][ct] = __builtin_amdgcn_mfma_f32_16x16x32_bf16(af[rt], bfr[ct], acc[rt][ct], 0, 0, 0);
        __syncthreads();
    }

    const int rg = (lane >> 4) * 4;
    #pragma unroll
    for (int rt = 0; rt < 2; ++rt) {
        #pragma unroll
        for (int r = 0; r < 4; ++r) {
            int gr = row0 + wave * 32 + rt * 16 + rg + r;
            if (gr < M) {
                float sc = 1.0f;
                if constexpr (SCALE) sc = dsq[gr];
                #pragma unroll
                for (int ct = 0; ct < NCT; ++ct)
                    Cb[(size_t)gr * N + col0 + ct * 16 + r16] = f2bf(acc[rt][ct][r] * sc);
            }
        }
    }
}

// ---------------- CSR aggregation, D=256: half-wave per edge, u16x8; bf16 out ----------
__global__ __launch_bounds__(256) void k_agg256_b(const unsigned short* __restrict__ hb,
                                                  const int* __restrict__ row_start,
                                                  const unsigned short* __restrict__ pk2,
                                                  const float* __restrict__ dsq,
                                                  const float* __restrict__ b,
                                                  unsigned short* __restrict__ outb) {
    int d = blockIdx.x * 4 + (threadIdx.x >> 6);
    if (d >= NN) return;
    const int lane = threadIdx.x & 63;
    const int eh = lane >> 5;          // half index: edge slot
    const int ch8 = (lane & 31) * 8;   // channel base (8 bf16 per lane)
    int rs = row_start[d], re = row_start[d + 1];
    float a0[8] = {}, a1[8] = {};
    int j = rs;
    for (; j + 4 <= re; j += 4) {
        int s0 = (int)pk2[j + eh];
        int s1 = (int)pk2[j + 2 + eh];
        u16x8 v0 = *reinterpret_cast<const u16x8*>(hb + (size_t)s0 * 256 + ch8);
        u16x8 v1 = *reinterpret_cast<const u16x8*>(hb + (size_t)s1 * 256 + ch8);
        #pragma unroll
        for (int t = 0; t < 8; ++t) { a0[t] += bf2f(v0[t]); a1[t] += bf2f(v1[t]); }
    }
    for (; j < re; j += 2) {
        int idx = j + eh;
        if (idx < re) {
            int s0 = (int)pk2[idx];
            u16x8 v0 = *reinterpret_cast<const u16x8*>(hb + (size_t)s0 * 256 + ch8);
            #pragma unroll
            for (int t = 0; t < 8; ++t) a0[t] += bf2f(v0[t]);
        }
    }
    #pragma unroll
    for (int t = 0; t < 8; ++t) {
        a0[t] += a1[t];
        a0[t] += __shfl_xor(a0[t], 32, 64);
    }
    if (eh == 0) {
        float sd = dsq[d];
        u16x8 hv = *reinterpret_cast<const u16x8*>(hb + (size_t)d * 256 + ch8);
        u16x8 ov;
        #pragma unroll
        for (int t = 0; t < 8; ++t)
            ov[t] = f2bf(fmaf(sd, a0[t] + bf2f(hv[t]), b[ch8 + t]));
        *reinterpret_cast<u16x8*>(outb + (size_t)d * 256 + ch8) = ov;
    }
}

// ---------------- CSR aggregation, D=64: quarter-wave per edge, ushort4; bf16 out ------
template <bool RELU>
__global__ __launch_bounds__(256) void k_agg64_b(const unsigned short* __restrict__ hb,
                                                 const int* __restrict__ row_start,
                                                 const unsigned short* __restrict__ pk2,
                                                 const float* __restrict__ dsq,
                                                 const float* __restrict__ b,
                                                 unsigned short* __restrict__ outb) {
    int d = blockIdx.x * 4 + (threadIdx.x >> 6);
    if (d >= NN) return;
    const int lane = threadIdx.x & 63;
    const int q = lane >> 4;           // quarter index: edge slot
    const int ch4 = (lane & 15) * 4;   // channel base (4 bf16 per lane)
    int rs = row_start[d], re = row_start[d + 1];
    float a0[4] = {}, a1[4] = {};
    int j = rs;
    for (; j + 8 <= re; j += 8) {
        int s0 = (int)pk2[j + q];
        int s1 = (int)pk2[j + 4 + q];
        ushort4 v0 = *reinterpret_cast<const ushort4*>(hb + (size_t)s0 * 64 + ch4);
        ushort4 v1 = *reinterpret_cast<const ushort4*>(hb + (size_t)s1 * 64 + ch4);
        a0[0] += bf2f(v0.x); a0[1] += bf2f(v0.y); a0[2] += bf2f(v0.z); a0[3] += bf2f(v0.w);
        a1[0] += bf2f(v1.x); a1[1] += bf2f(v1.y); a1[2] += bf2f(v1.z); a1[3] += bf2f(v1.w);
    }
    for (; j < re; j += 4) {
        int idx = j + q;
        if (idx < re) {
            int s0 = (int)pk2[idx];
            ushort4 v0 = *reinterpret_cast<const ushort4*>(hb + (size_t)s0 * 64 + ch4);
            a0[0] += bf2f(v0.x); a0[1] += bf2f(v0.y); a0[2] += bf2f(v0.z); a0[3] += bf2f(v0.w);
        }
    }
    #pragma unroll
    for (int t = 0; t < 4; ++t) {
        a0[t] += a1[t];
        a0[t] += __shfl_xor(a0[t], 16, 64);
        a0[t] += __shfl_xor(a0[t], 32, 64);
    }
    if (q == 0) {
        float sd = dsq[d];
        ushort4 hv = *reinterpret_cast<const ushort4*>(hb + (size_t)d * 64 + ch4);
        float o0 = fmaf(sd, a0[0] + bf2f(hv.x), b[ch4 + 0]);
        float o1 = fmaf(sd, a0[1] + bf2f(hv.y), b[ch4 + 1]);
        float o2 = fmaf(sd, a0[2] + bf2f(hv.z), b[ch4 + 2]);
        float o3 = fmaf(sd, a0[3] + bf2f(hv.w), b[ch4 + 3]);
        if (RELU) {
            o0 = fmaxf(o0, 0.0f); o1 = fmaxf(o1, 0.0f);
            o2 = fmaxf(o2, 0.0f); o3 = fmaxf(o3, 0.0f);
        }
        ushort4 ov;
        ov.x = f2bf(o0); ov.y = f2bf(o1); ov.z = f2bf(o2); ov.w = f2bf(o3);
        *reinterpret_cast<ushort4*>(outb + (size_t)d * 64 + ch4) = ov;
    }
}

// ---------------- BatchNorm stats: wide grid + replicated sums ----------------
// sums: BN_REPS replicas of [s(C)][ss(C)], replica = blockIdx & (BN_REPS-1).
template <int C>
__global__ __launch_bounds__(256) void k_bn_stats_b(const unsigned short* __restrict__ x,
                                                    float* __restrict__ sums) {
    constexpr int CG = C / 8;        // channel groups per row (32 or 8)
    constexpr int R = 256 / CG;      // rows per block-iteration (8 or 32)
    const int t = threadIdx.x;
    const int cg = t % CG;
    const int slot = t / CG;
    float* __restrict__ srep = sums + (blockIdx.x & (BN_REPS - 1)) * 2 * C;

    float s[8] = {}, ss[8] = {};
    for (int r = blockIdx.x * R + slot; r < NN; r += gridDim.x * R) {
        u16x8 v = *reinterpret_cast<const u16x8*>(x + (size_t)r * C + cg * 8);
        #pragma unroll
        for (int j = 0; j < 8; ++j) {
            float f = bf2f(v[j]);
            s[j] += f;
            ss[j] += f * f;
        }
    }

    __shared__ float ls[256][8];
    __shared__ float lss[256][8];
    #pragma unroll
    for (int j = 0; j < 8; ++j) { ls[t][j] = s[j]; lss[t][j] = ss[j]; }
    __syncthreads();
    if (slot == 0) {
        #pragma unroll 4
        for (int k = 1; k < R; ++k)
            #pragma unroll
            for (int j = 0; j < 8; ++j) {
                s[j] += ls[cg + k * CG][j];
                ss[j] += lss[cg + k * CG][j];
            }
        #pragma unroll
        for (int j = 0; j < 8; ++j) {
            atomicAdd(&srep[cg * 8 + j], s[j]);
            atomicAdd(&srep[C + cg * 8 + j], ss[j]);
        }
    }
}

// ---------------- edge MLP v6: W2 frags in regs, no barrier, 4 blocks/CU ----------------
__global__ __launch_bounds__(EB) void k_edge_mlp6(const unsigned short* __restrict__ AB,
                                                  const int* __restrict__ src,
                                                  const int* __restrict__ dst,
                                                  const float* __restrict__ b1,
                                                  const float* __restrict__ W2,
                                                  const float* __restrict__ b2,
                                                  const float* __restrict__ W3,
                                                  const float* __restrict__ b3,
                                                  float* __restrict__ out) {
    __shared__ unsigned short h1s[EB * 72];      // [edge][k] stride 72; wave-local rows
    const int tid = threadIdx.x;
    const int w = tid >> 6, lane = tid & 63;
    const int base = blockIdx.x * EB + w * 64;

    const int r16 = lane & 15;
    const int kg = (lane >> 4) * 8;
    const int rg = (lane >> 4) * 4;

    // ---- W2 fragments (hi + lo residual) straight into registers ----
    bf16x8f b0h[2], b0l[2], b1h[2], b1l[2];
    #pragma unroll
    for (int ks = 0; ks < 2; ++ks) {
        u16x8 h0, l0, h1r, l1r;
        #pragma unroll
        for (int j = 0; j < 8; ++j) {
            int k = ks * 32 + kg + j;
            float v0 = W2[(size_t)k * 32 + r16];
            float v1 = W2[(size_t)k * 32 + 16 + r16];
            unsigned short hi0 = f2bf(v0);
            unsigned short hi1 = f2bf(v1);
            h0[j] = hi0; l0[j] = f2bf(v0 - bf2f(hi0));
            h1r[j] = hi1; l1r[j] = f2bf(v1 - bf2f(hi1));
        }
        b0h[ks] = __builtin_bit_cast(bf16x8f, h0);
        b0l[ks] = __builtin_bit_cast(bf16x8f, l0);
        b1h[ks] = __builtin_bit_cast(bf16x8f, h1r);
        b1l[ks] = __builtin_bit_cast(bf16x8f, l1r);
    }

    // ---- phase 1: gather h1 = relu(A[s]+B[d]+b1) -> LDS (wave-local rows) ----
    int ee = base + lane;                 // NE % EB == 0
    int se = src[ee];
    int de = dst[ee];

    const int eh = lane >> 5;
    const int ch2 = (lane & 31) * 2;
    const float b1v0 = b1[ch2], b1v1 = b1[ch2 + 1];

    #pragma unroll 8
    for (int i = 0; i < 32; ++i) {
        int ei = 2 * i + eh;
        int s = __shfl(se, ei, 64);
        int d = __shfl(de, ei, 64);
        ushort2 ua = *reinterpret_cast<const ushort2*>(AB + (size_t)s * 128 + ch2);
        ushort2 ub = *reinterpret_cast<const ushort2*>(AB + (size_t)d * 128 + 64 + ch2);
        float v0 = fmaxf(bf2f(ua.x) + bf2f(ub.x) + b1v0, 0.0f);
        float v1 = fmaxf(bf2f(ua.y) + bf2f(ub.y) + b1v1, 0.0f);
        ushort2 uo;
        uo.x = f2bf(v0);
        uo.y = f2bf(v1);
        *reinterpret_cast<ushort2*>(&h1s[(w * 64 + ei) * 72 + ch2]) = uo;
    }
    // no barrier: each wave reads only its own h1s rows

    // ---- phase 2: h2 = relu(h1 @ W2 + b2) via MFMA; out = h2 @ W3 + b3 ----
    const float b2c0 = b2[r16], b2c1 = b2[16 + r16];
    const float w300 = W3[r16 * 2], w301 = W3[r16 * 2 + 1];
    const float w310 = W3[(16 + r16) * 2], w311 = W3[(16 + r16) * 2 + 1];
    const float b30 = b3[0], b31 = b3[1];

    #pragma unroll
    for (int rt = 0; rt < 4; ++rt) {
        f32x4 acc0 = {}, acc1 = {};
        #pragma unroll
        for (int ks = 0; ks < 2; ++ks) {
            bf16x8f af = __builtin_bit_cast(bf16x8f,
                *reinterpret_cast<const u16x8*>(&h1s[(w * 64 + rt * 16 + r16) * 72 + ks * 32 + kg]));
            acc0 = __builtin_amdgcn_mfma_f32_16x16x32_bf16(af, b0h[ks], acc0, 0, 0, 0);
            acc0 = __builtin_amdgcn_mfma_f32_16x16x32_bf16(af, b0l[ks], acc0, 0, 0, 0);
            acc1 = __builtin_amdgcn_mfma_f32_16x16x32_bf16(af, b1h[ks], acc1, 0, 0, 0);
            acc1 = __builtin_amdgcn_mfma_f32_16x16x32_bf16(af, b1l[ks], acc1, 0, 0, 0);
        }
        #pragma unroll
        for (int r = 0; r < 4; ++r) {
            float h20 = fmaxf(acc0[r] + b2c0, 0.0f);
            float h21 = fmaxf(acc1[r] + b2c1, 0.0f);
            float p0 = fmaf(h20, w300, h21 * w310);
            float p1 = fmaf(h20, w301, h21 * w311);
            p0 += __shfl_xor(p0, 1, 64); p0 += __shfl_xor(p0, 2, 64);
            p0 += __shfl_xor(p0, 4, 64); p0 += __shfl_xor(p0, 8, 64);
            p1 += __shfl_xor(p1, 1, 64); p1 += __shfl_xor(p1, 2, 64);
            p1 += __shfl_xor(p1, 4, 64); p1 += __shfl_xor(p1, 8, 64);
            if (r16 == 0) {
                int e = base + rt * 16 + rg + r;
                *reinterpret_cast<float2*>(out + (size_t)2 * e) = make_float2(p0 + b30, p1 + b31);
            }
        }
    }
}

// ---------------- launch ----------------
extern "C" void kernel_launch(void* const* d_in, const int* in_sizes, int n_in,
                              void* d_out, int out_size, void* d_ws, size_t ws_size,
                              hipStream_t stream) {
    const float* x    = (const float*)d_in[0];
    const int*   ei   = (const int*)d_in[1];
    const int*   src  = ei;
    const int*   dst  = ei + NE;
    const float* W1   = (const float*)d_in[2];
    const float* b1   = (const float*)d_in[3];
    const float* g1   = (const float*)d_in[4];
    const float* be1  = (const float*)d_in[5];
    const float* W2   = (const float*)d_in[6];
    const float* b2   = (const float*)d_in[7];
    const float* g2   = (const float*)d_in[8];
    const float* be2  = (const float*)d_in[9];
    const float* W3   = (const float*)d_in[10];
    const float* b3   = (const float*)d_in[11];
    const float* We1  = (const float*)d_in[12];
    const float* bme1 = (const float*)d_in[13];
    const float* We2  = (const float*)d_in[14];
    const float* bme2 = (const float*)d_in[15];
    const float* We3  = (const float*)d_in[16];
    const float* bme3 = (const float*)d_in[17];
    float* out = (float*)d_out;
    char* ws = (char*)d_ws;

    // zero-region (one memset): cnt | sums1 (8 x 512) | sums2 (8 x 128)
    int*   cnt      = (int*)ws;                           ws += NPAD * 4;
    float* sums1    = (float*)ws;                         ws += BN_REPS * 512 * 4;
    float* sums2    = (float*)ws;                         ws += BN_REPS * 128 * 4;
    const size_t zero_bytes = (size_t)NPAD * 4 + (size_t)BN_REPS * 512 * 4 + (size_t)BN_REPS * 128 * 4;
    // non-zeroed
    float* dsq      = (float*)ws;                         ws += NPAD * 4;
    int*   cursor   = (int*)ws;                           ws += NPAD * 4;
    int*   bsum     = (int*)ws;                           ws += 256 * 4;
    int*   row_start= (int*)ws;                           ws += (NPAD + 16) * 4;
    unsigned short* pk2 = (unsigned short*)ws;            ws += (size_t)NE * 2;
    ws += 64;  // alignment pad
    unsigned short* bufHb = (unsigned short*)ws;          ws += (size_t)NN * 256 * 2;
    unsigned short* bufOb = (unsigned short*)ws;          ws += (size_t)NN * 256 * 2;

    const int nblkE = (NE + 255) / 256;
    const int nblkNode = (NN + 3) / 4;
    const int gy = (NN + 127) / 128;   // 391

    // ---- CSR build + degree terms ----
    hipMemsetAsync(cnt, 0, zero_bytes, stream);
    k_count_int<<<nblkE, 256, 0, stream>>>(dst, cnt);
    k_bsum<<<SCAN_BLOCKS, 256, 0, stream>>>(cnt, bsum);
    k_scan_fin<<<SCAN_BLOCKS, 256, 0, stream>>>(cnt, bsum, row_start, cursor, dsq);
    k_fill<<<nblkE, 256, 0, stream>>>(src, dst, cursor, pk2);

    // ---- layer 1: 256 -> 256 MFMA (fp32 A, bf16+dsq-scaled out), agg, BN stats ----
    k_gemm_mfma<128, false, true, false, false><<<dim3(2, gy), 256, 0, stream>>>(
        x, nullptr, W1, bufHb, NN, 256, 256, nullptr, nullptr, nullptr, dsq);
    k_agg256_b<<<nblkNode, 256, 0, stream>>>(bufHb, row_start, pk2, dsq, b1, bufOb);
    k_bn_stats_b<256><<<BN_GRID, 256, 0, stream>>>(bufOb, sums1);

    // ---- layer 2: A = BN1(bufOb) fused bf16 (stats derived in-block); 256 -> 64 MFMA ----
    k_gemm_mfma<64, true, true, true, false><<<dim3(1, gy), 256, 0, stream>>>(
        nullptr, bufOb, W2, bufHb, NN, 256, 64, sums1, g1, be1, dsq);
    k_agg64_b<false><<<nblkNode, 256, 0, stream>>>(bufHb, row_start, pk2, dsq, b2, bufOb);
    k_bn_stats_b<64><<<BN_GRID, 256, 0, stream>>>(bufOb, sums2);

    // ---- layer 3: A = BN2(bufOb) fused; 64 -> 64 MFMA; agg + relu ----
    k_gemm_mfma<64, true, true, true, false><<<dim3(1, gy), 256, 0, stream>>>(
        nullptr, bufOb, W3, bufHb, NN, 64, 64, sums2, g2, be2, dsq);
    k_agg64_b<true><<<nblkNode, 256, 0, stream>>>(bufHb, row_start, pk2, dsq, b3, bufOb);

    // ---- layer 4: 64 -> 64 MFMA (bf16 A, same W3/b3, no relu) -> emb in bufOb ----
    k_gemm_mfma<64, false, true, true, false><<<dim3(1, gy), 256, 0, stream>>>(
        nullptr, bufOb, W3, bufHb, NN, 64, 64, nullptr, nullptr, nullptr, dsq);
    k_agg64_b<false><<<nblkNode, 256, 0, stream>>>(bufHb, row_start, pk2, dsq, b3, bufOb);

    // ---- edge MLP: fused A|B gemm (bf16 A) -> AB[NN][128] bf16, then MLP ----
    unsigned short* ABbuf = bufHb;   // NN*128 ushort
    k_gemm_mfma<128, false, false, true, true><<<dim3(1, gy), 256, 0, stream>>>(
        nullptr, bufOb, We1, ABbuf, NN, 64, 128, nullptr, nullptr, nullptr, nullptr);
    k_edge_mlp6<<<NE / EB, EB, 0, stream>>>(ABbuf, src, dst, bme1, We2, bme2, We3, bme3, out);

    (void)in_sizes; (void)n_in; (void)out_size; (void)ws_size;
}

// Round 24
// 398.490 us; speedup vs baseline: 1.2033x; 1.2033x over previous
//
#include <hip/hip_runtime.h>
#include <hip/hip_bf16.h>
#include <cstddef>

#define NN 50000
#define NE 800000
#define NPAD 50176
#define SCAN_BLOCKS 196   // ceil(NN/256)
#define BN_EPS 1e-5f
#define EB 256            // edges per block in edge MLP (4 waves); NE % EB == 0
#define BN_PARTS 64       // partial-reduction blocks for BN stats (no atomics)

typedef __bf16 bf16x8f __attribute__((ext_vector_type(8)));
typedef unsigned short u16x8 __attribute__((ext_vector_type(8)));
typedef float f32x4 __attribute__((ext_vector_type(4)));

__device__ __forceinline__ unsigned short f2bf(float f) {
    __hip_bfloat16 h = __float2bfloat16(f);
    return *reinterpret_cast<unsigned short*>(&h);
}
__device__ __forceinline__ float bf2f(unsigned short u) {
    return __uint_as_float(((unsigned int)u) << 16);
}

// ---------------- CSR build ----------------
__global__ __launch_bounds__(256) void k_count_int(const int* __restrict__ dst,
                                                   int* __restrict__ cnt) {
    int e = blockIdx.x * 256 + threadIdx.x;
    if (e < NE) atomicAdd(&cnt[dst[e]], 1);
}

__global__ __launch_bounds__(256) void k_bsum(const int* __restrict__ cnt,
                                              int* __restrict__ bsum) {
    __shared__ int red[4];
    int i = blockIdx.x * 256 + threadIdx.x;
    int v = (i < NN) ? cnt[i] : 0;
    #pragma unroll
    for (int off = 32; off > 0; off >>= 1) v += __shfl_down(v, off, 64);
    int lane = threadIdx.x & 63, w = threadIdx.x >> 6;
    if (lane == 0) red[w] = v;
    __syncthreads();
    if (threadIdx.x == 0) bsum[blockIdx.x] = red[0] + red[1] + red[2] + red[3];
}

// per-block exclusive scan; block base computed from raw bsum
__global__ __launch_bounds__(256) void k_scan_fin(const int* __restrict__ cnt,
                                                  const int* __restrict__ bsum,
                                                  int* __restrict__ row_start,
                                                  int* __restrict__ cursor,
                                                  float* __restrict__ dsq) {
    __shared__ int tmp[256];
    __shared__ int red[4];
    const int t = threadIdx.x;

    int pv = (t < blockIdx.x) ? bsum[t] : 0;   // blockIdx.x < 256
    #pragma unroll
    for (int off = 32; off > 0; off >>= 1) pv += __shfl_down(pv, off, 64);
    if ((t & 63) == 0) red[t >> 6] = pv;
    __syncthreads();
    const int blockbase = red[0] + red[1] + red[2] + red[3];

    int i = blockIdx.x * 256 + t;
    int c = (i < NN) ? cnt[i] : 0;
    tmp[t] = c;
    __syncthreads();
    #pragma unroll
    for (int off = 1; off < 256; off <<= 1) {
        int u = (t >= off) ? tmp[t - off] : 0;
        __syncthreads();
        tmp[t] += u;
        __syncthreads();
    }
    int excl = tmp[t] - c + blockbase;
    if (i < NN) {
        row_start[i] = excl;
        cursor[i] = excl;
        dsq[i] = rsqrtf((float)c + 1.0f);
    }
    if (i == 0) row_start[NN] = NE;
}

// fill compact CSR entries: src as ushort (NN < 65536)
__global__ __launch_bounds__(256) void k_fill(const int* __restrict__ src,
                                              const int* __restrict__ dst,
                                              int* __restrict__ cursor,
                                              unsigned short* __restrict__ pk2) {
    int e = blockIdx.x * 256 + threadIdx.x;
    if (e < NE) {
        int pos = atomicAdd(&cursor[dst[e]], 1);
        pk2[pos] = (unsigned short)src[e];
    }
}

// ---------------- MFMA bf16 GEMM ----------------
// ABF: A is bf16 (ushort). BNA: fused BN+relu on A; `sums` holds BN_PARTS partials of
// [s(K)][ss(K)] (stride 2K each, plain stores); each block reduces them into LDS.
// SCALE: out *= dsq[row]. FUSEB: B is We1[128][64]; fused N=128 output.
template <int BNT, bool BNA, bool SCALE, bool ABF, bool FUSEB>
__global__ __launch_bounds__(256) void k_gemm_mfma(const float* __restrict__ A,
                                                   const unsigned short* __restrict__ Ab,
                                                   const float* __restrict__ B,
                                                   unsigned short* __restrict__ Cb,
                                                   int M, int K, int N,
                                                   const float* __restrict__ sums,
                                                   const float* __restrict__ g,
                                                   const float* __restrict__ be,
                                                   const float* __restrict__ dsq) {
    __shared__ unsigned short As[128 * 56];
    __shared__ unsigned short Bs[BNT * 56];
    __shared__ float bn_mean[256];
    __shared__ float bn_istd[256];
    const int tid = threadIdx.x;
    const int lane = tid & 63, wave = tid >> 6;
    const int row0 = blockIdx.y * 128, col0 = blockIdx.x * BNT;
    constexpr int NCT = BNT / 16;

    if constexpr (BNA) {
        if (tid < K) {
            float s = 0.0f, ss = 0.0f;
            for (int p = 0; p < BN_PARTS; ++p) {
                s += sums[p * 2 * K + tid];
                ss += sums[p * 2 * K + K + tid];
            }
            const float invN = 1.0f / (float)NN;
            float mean = s * invN;
            float var = ss * invN - mean * mean;
            bn_mean[tid] = mean;
            bn_istd[tid] = rsqrtf(var + BN_EPS);
        }
        __syncthreads();
    }

    f32x4 acc[2][NCT] = {};

    const int r16 = lane & 15;
    const int kg = (lane >> 4) * 8;

    for (int k0 = 0; k0 < K; k0 += 32) {
        // ---- stage A: 128 rows x 32 k ----
        {
            int row = tid >> 1;
            int kh = (tid & 1) * 16;
            int gr = row0 + row;
            unsigned short* dp = &As[row * 56 + kh];
            if constexpr (!ABF) {
                unsigned short tmp[16];
                if (gr < M) {
                    const float* ap = A + (size_t)gr * K + k0 + kh;
                    #pragma unroll
                    for (int j = 0; j < 16; ++j) {
                        float v = ap[j];
                        if constexpr (BNA) {
                            int c = k0 + kh + j;
                            v = fmaxf((v - bn_mean[c]) * bn_istd[c] * g[c] + be[c], 0.0f);
                        }
                        tmp[j] = f2bf(v);
                    }
                } else {
                    #pragma unroll
                    for (int j = 0; j < 16; ++j) tmp[j] = 0;
                }
                *reinterpret_cast<u16x8*>(dp) = *reinterpret_cast<const u16x8*>(&tmp[0]);
                *reinterpret_cast<u16x8*>(dp + 8) = *reinterpret_cast<const u16x8*>(&tmp[8]);
            } else {
                u16x8 t0 = {}, t1 = {};
                if (gr < M) {
                    const unsigned short* ap = Ab + (size_t)gr * K + k0 + kh;
                    t0 = *reinterpret_cast<const u16x8*>(ap);
                    t1 = *reinterpret_cast<const u16x8*>(ap + 8);
                    if constexpr (BNA) {
                        #pragma unroll
                        for (int j = 0; j < 8; ++j) {
                            int c0 = k0 + kh + j, c1 = k0 + kh + 8 + j;
                            float v0 = fmaxf((bf2f(t0[j]) - bn_mean[c0]) * bn_istd[c0] * g[c0] + be[c0], 0.0f);
                            float v1 = fmaxf((bf2f(t1[j]) - bn_mean[c1]) * bn_istd[c1] * g[c1] + be[c1], 0.0f);
                            t0[j] = f2bf(v0);
                            t1[j] = f2bf(v1);
                        }
                    }
                }
                *reinterpret_cast<u16x8*>(dp) = t0;
                *reinterpret_cast<u16x8*>(dp + 8) = t1;
            }
        }
        // ---- stage B transposed: Bs[col][k] ----
        {
            constexpr int JC = (BNT == 128) ? 16 : 8;
            int col = tid & (BNT - 1);
            int kh = (tid / BNT) * JC;
            unsigned short tmp[JC];
            #pragma unroll
            for (int j = 0; j < JC; ++j) {
                float bv;
                if constexpr (FUSEB) {
                    int kk = k0 + kh + j;
                    int c = col0 + col;
                    bv = (c < 64) ? B[(size_t)kk * 64 + c]
                                  : B[(size_t)(64 + kk) * 64 + (c - 64)];
                } else {
                    bv = B[(size_t)(k0 + kh + j) * N + col0 + col];
                }
                tmp[j] = f2bf(bv);
            }
            unsigned short* dp = &Bs[col * 56 + kh];
            #pragma unroll
            for (int j = 0; j < JC; j += 8)
                *reinterpret_cast<u16x8*>(dp + j) = *reinterpret_cast<const u16x8*>(&tmp[j]);
        }
        __syncthreads();

        bf16x8f af[2];
        bf16x8f bfr[NCT];
        #pragma unroll
        for (int rt = 0; rt < 2; ++rt)
            af[rt] = __builtin_bit_cast(bf16x8f,
                *reinterpret_cast<const u16x8*>(&As[(wave * 32 + rt * 16 + r16) * 56 + kg]));
        #pragma unroll
        for (int ct = 0; ct < NCT; ++ct)
            bfr[ct] = __builtin_bit_cast(bf16x8f,
                *reinterpret_cast<const u16x8*>(&Bs[(ct * 16 + r16) * 56 + kg]));
        #pragma unroll
        for (int rt = 0; rt < 2; ++rt)
            #pragma unroll
            for (int ct = 0; ct < NCT; ++ct)
                acc[rt][ct] = __builtin_amdgcn_mfma_f32_16x16x32_bf16(af[rt], bfr[ct], acc[rt][ct], 0, 0, 0);
        __syncthreads();
    }

    const int rg = (lane >> 4) * 4;
    #pragma unroll
    for (int rt = 0; rt < 2; ++rt) {
        #pragma unroll
        for (int r = 0; r < 4; ++r) {
            int gr = row0 + wave * 32 + rt * 16 + rg + r;
            if (gr < M) {
                float sc = 1.0f;
                if constexpr (SCALE) sc = dsq[gr];
                #pragma unroll
                for (int ct = 0; ct < NCT; ++ct)
                    Cb[(size_t)gr * N + col0 + ct * 16 + r16] = f2bf(acc[rt][ct][r] * sc);
            }
        }
    }
}

// ---------------- CSR aggregation, D=256: half-wave per edge, u16x8; bf16 out ----------
__global__ __launch_bounds__(256) void k_agg256_b(const unsigned short* __restrict__ hb,
                                                  const int* __restrict__ row_start,
                                                  const unsigned short* __restrict__ pk2,
                                                  const float* __restrict__ dsq,
                                                  const float* __restrict__ b,
                                                  unsigned short* __restrict__ outb) {
    int d = blockIdx.x * 4 + (threadIdx.x >> 6);
    if (d >= NN) return;
    const int lane = threadIdx.x & 63;
    const int eh = lane >> 5;          // half index: edge slot
    const int ch8 = (lane & 31) * 8;   // channel base (8 bf16 per lane)
    int rs = row_start[d], re = row_start[d + 1];
    float a0[8] = {}, a1[8] = {};
    int j = rs;
    for (; j + 4 <= re; j += 4) {
        int s0 = (int)pk2[j + eh];
        int s1 = (int)pk2[j + 2 + eh];
        u16x8 v0 = *reinterpret_cast<const u16x8*>(hb + (size_t)s0 * 256 + ch8);
        u16x8 v1 = *reinterpret_cast<const u16x8*>(hb + (size_t)s1 * 256 + ch8);
        #pragma unroll
        for (int t = 0; t < 8; ++t) { a0[t] += bf2f(v0[t]); a1[t] += bf2f(v1[t]); }
    }
    for (; j < re; j += 2) {
        int idx = j + eh;
        if (idx < re) {
            int s0 = (int)pk2[idx];
            u16x8 v0 = *reinterpret_cast<const u16x8*>(hb + (size_t)s0 * 256 + ch8);
            #pragma unroll
            for (int t = 0; t < 8; ++t) a0[t] += bf2f(v0[t]);
        }
    }
    #pragma unroll
    for (int t = 0; t < 8; ++t) {
        a0[t] += a1[t];
        a0[t] += __shfl_xor(a0[t], 32, 64);
    }
    if (eh == 0) {
        float sd = dsq[d];
        u16x8 hv = *reinterpret_cast<const u16x8*>(hb + (size_t)d * 256 + ch8);
        u16x8 ov;
        #pragma unroll
        for (int t = 0; t < 8; ++t)
            ov[t] = f2bf(fmaf(sd, a0[t] + bf2f(hv[t]), b[ch8 + t]));
        *reinterpret_cast<u16x8*>(outb + (size_t)d * 256 + ch8) = ov;
    }
}

// ---------------- CSR aggregation, D=64: quarter-wave per edge, ushort4; bf16 out ------
template <bool RELU>
__global__ __launch_bounds__(256) void k_agg64_b(const unsigned short* __restrict__ hb,
                                                 const int* __restrict__ row_start,
                                                 const unsigned short* __restrict__ pk2,
                                                 const float* __restrict__ dsq,
                                                 const float* __restrict__ b,
                                                 unsigned short* __restrict__ outb) {
    int d = blockIdx.x * 4 + (threadIdx.x >> 6);
    if (d >= NN) return;
    const int lane = threadIdx.x & 63;
    const int q = lane >> 4;           // quarter index: edge slot
    const int ch4 = (lane & 15) * 4;   // channel base (4 bf16 per lane)
    int rs = row_start[d], re = row_start[d + 1];
    float a0[4] = {}, a1[4] = {};
    int j = rs;
    for (; j + 8 <= re; j += 8) {
        int s0 = (int)pk2[j + q];
        int s1 = (int)pk2[j + 4 + q];
        ushort4 v0 = *reinterpret_cast<const ushort4*>(hb + (size_t)s0 * 64 + ch4);
        ushort4 v1 = *reinterpret_cast<const ushort4*>(hb + (size_t)s1 * 64 + ch4);
        a0[0] += bf2f(v0.x); a0[1] += bf2f(v0.y); a0[2] += bf2f(v0.z); a0[3] += bf2f(v0.w);
        a1[0] += bf2f(v1.x); a1[1] += bf2f(v1.y); a1[2] += bf2f(v1.z); a1[3] += bf2f(v1.w);
    }
    for (; j < re; j += 4) {
        int idx = j + q;
        if (idx < re) {
            int s0 = (int)pk2[idx];
            ushort4 v0 = *reinterpret_cast<const ushort4*>(hb + (size_t)s0 * 64 + ch4);
            a0[0] += bf2f(v0.x); a0[1] += bf2f(v0.y); a0[2] += bf2f(v0.z); a0[3] += bf2f(v0.w);
        }
    }
    #pragma unroll
    for (int t = 0; t < 4; ++t) {
        a0[t] += a1[t];
        a0[t] += __shfl_xor(a0[t], 16, 64);
        a0[t] += __shfl_xor(a0[t], 32, 64);
    }
    if (q == 0) {
        float sd = dsq[d];
        ushort4 hv = *reinterpret_cast<const ushort4*>(hb + (size_t)d * 64 + ch4);
        float o0 = fmaf(sd, a0[0] + bf2f(hv.x), b[ch4 + 0]);
        float o1 = fmaf(sd, a0[1] + bf2f(hv.y), b[ch4 + 1]);
        float o2 = fmaf(sd, a0[2] + bf2f(hv.z), b[ch4 + 2]);
        float o3 = fmaf(sd, a0[3] + bf2f(hv.w), b[ch4 + 3]);
        if (RELU) {
            o0 = fmaxf(o0, 0.0f); o1 = fmaxf(o1, 0.0f);
            o2 = fmaxf(o2, 0.0f); o3 = fmaxf(o3, 0.0f);
        }
        ushort4 ov;
        ov.x = f2bf(o0); ov.y = f2bf(o1); ov.z = f2bf(o2); ov.w = f2bf(o3);
        *reinterpret_cast<ushort4*>(outb + (size_t)d * 64 + ch4) = ov;
    }
}

// ---------------- BatchNorm stats: two-stage, NO atomics ----------------
// grid = BN_PARTS blocks; block b writes its partial [s(C)][ss(C)] at partials + b*2C.
template <int C>
__global__ __launch_bounds__(256) void k_bn_stats_b(const unsigned short* __restrict__ x,
                                                    float* __restrict__ partials) {
    constexpr int CG = C / 8;        // channel groups per row (32 or 8)
    constexpr int R = 256 / CG;      // rows per block-iteration (8 or 32)
    const int t = threadIdx.x;
    const int cg = t % CG;
    const int slot = t / CG;

    float s[8] = {}, ss[8] = {};
    for (int r = blockIdx.x * R + slot; r < NN; r += gridDim.x * R) {
        u16x8 v = *reinterpret_cast<const u16x8*>(x + (size_t)r * C + cg * 8);
        #pragma unroll
        for (int j = 0; j < 8; ++j) {
            float f = bf2f(v[j]);
            s[j] += f;
            ss[j] += f * f;
        }
    }

    __shared__ float ls[256][8];
    __shared__ float lss[256][8];
    #pragma unroll
    for (int j = 0; j < 8; ++j) { ls[t][j] = s[j]; lss[t][j] = ss[j]; }
    __syncthreads();
    if (slot == 0) {
        #pragma unroll 4
        for (int k = 1; k < R; ++k)
            #pragma unroll
            for (int j = 0; j < 8; ++j) {
                s[j] += ls[cg + k * CG][j];
                ss[j] += lss[cg + k * CG][j];
            }
        float* dst = partials + (size_t)blockIdx.x * 2 * C;
        #pragma unroll
        for (int j = 0; j < 8; ++j) {
            dst[cg * 8 + j] = s[j];
            dst[C + cg * 8 + j] = ss[j];
        }
    }
}

// ---------------- edge MLP v6: W2 frags in regs, no barrier, 4 blocks/CU ----------------
__global__ __launch_bounds__(EB) void k_edge_mlp6(const unsigned short* __restrict__ AB,
                                                  const int* __restrict__ src,
                                                  const int* __restrict__ dst,
                                                  const float* __restrict__ b1,
                                                  const float* __restrict__ W2,
                                                  const float* __restrict__ b2,
                                                  const float* __restrict__ W3,
                                                  const float* __restrict__ b3,
                                                  float* __restrict__ out) {
    __shared__ unsigned short h1s[EB * 72];      // [edge][k] stride 72; wave-local rows
    const int tid = threadIdx.x;
    const int w = tid >> 6, lane = tid & 63;
    const int base = blockIdx.x * EB + w * 64;

    const int r16 = lane & 15;
    const int kg = (lane >> 4) * 8;
    const int rg = (lane >> 4) * 4;

    // ---- W2 fragments (hi + lo residual) straight into registers ----
    bf16x8f b0h[2], b0l[2], b1h[2], b1l[2];
    #pragma unroll
    for (int ks = 0; ks < 2; ++ks) {
        u16x8 h0, l0, h1r, l1r;
        #pragma unroll
        for (int j = 0; j < 8; ++j) {
            int k = ks * 32 + kg + j;
            float v0 = W2[(size_t)k * 32 + r16];
            float v1 = W2[(size_t)k * 32 + 16 + r16];
            unsigned short hi0 = f2bf(v0);
            unsigned short hi1 = f2bf(v1);
            h0[j] = hi0; l0[j] = f2bf(v0 - bf2f(hi0));
            h1r[j] = hi1; l1r[j] = f2bf(v1 - bf2f(hi1));
        }
        b0h[ks] = __builtin_bit_cast(bf16x8f, h0);
        b0l[ks] = __builtin_bit_cast(bf16x8f, l0);
        b1h[ks] = __builtin_bit_cast(bf16x8f, h1r);
        b1l[ks] = __builtin_bit_cast(bf16x8f, l1r);
    }

    // ---- phase 1: gather h1 = relu(A[s]+B[d]+b1) -> LDS (wave-local rows) ----
    int ee = base + lane;                 // NE % EB == 0
    int se = src[ee];
    int de = dst[ee];

    const int eh = lane >> 5;
    const int ch2 = (lane & 31) * 2;
    const float b1v0 = b1[ch2], b1v1 = b1[ch2 + 1];

    #pragma unroll 8
    for (int i = 0; i < 32; ++i) {
        int ei = 2 * i + eh;
        int s = __shfl(se, ei, 64);
        int d = __shfl(de, ei, 64);
        ushort2 ua = *reinterpret_cast<const ushort2*>(AB + (size_t)s * 128 + ch2);
        ushort2 ub = *reinterpret_cast<const ushort2*>(AB + (size_t)d * 128 + 64 + ch2);
        float v0 = fmaxf(bf2f(ua.x) + bf2f(ub.x) + b1v0, 0.0f);
        float v1 = fmaxf(bf2f(ua.y) + bf2f(ub.y) + b1v1, 0.0f);
        ushort2 uo;
        uo.x = f2bf(v0);
        uo.y = f2bf(v1);
        *reinterpret_cast<ushort2*>(&h1s[(w * 64 + ei) * 72 + ch2]) = uo;
    }
    // no barrier: each wave reads only its own h1s rows

    // ---- phase 2: h2 = relu(h1 @ W2 + b2) via MFMA; out = h2 @ W3 + b3 ----
    const float b2c0 = b2[r16], b2c1 = b2[16 + r16];
    const float w300 = W3[r16 * 2], w301 = W3[r16 * 2 + 1];
    const float w310 = W3[(16 + r16) * 2], w311 = W3[(16 + r16) * 2 + 1];
    const float b30 = b3[0], b31 = b3[1];

    #pragma unroll
    for (int rt = 0; rt < 4; ++rt) {
        f32x4 acc0 = {}, acc1 = {};
        #pragma unroll
        for (int ks = 0; ks < 2; ++ks) {
            bf16x8f af = __builtin_bit_cast(bf16x8f,
                *reinterpret_cast<const u16x8*>(&h1s[(w * 64 + rt * 16 + r16) * 72 + ks * 32 + kg]));
            acc0 = __builtin_amdgcn_mfma_f32_16x16x32_bf16(af, b0h[ks], acc0, 0, 0, 0);
            acc0 = __builtin_amdgcn_mfma_f32_16x16x32_bf16(af, b0l[ks], acc0, 0, 0, 0);
            acc1 = __builtin_amdgcn_mfma_f32_16x16x32_bf16(af, b1h[ks], acc1, 0, 0, 0);
            acc1 = __builtin_amdgcn_mfma_f32_16x16x32_bf16(af, b1l[ks], acc1, 0, 0, 0);
        }
        #pragma unroll
        for (int r = 0; r < 4; ++r) {
            float h20 = fmaxf(acc0[r] + b2c0, 0.0f);
            float h21 = fmaxf(acc1[r] + b2c1, 0.0f);
            float p0 = fmaf(h20, w300, h21 * w310);
            float p1 = fmaf(h20, w301, h21 * w311);
            p0 += __shfl_xor(p0, 1, 64); p0 += __shfl_xor(p0, 2, 64);
            p0 += __shfl_xor(p0, 4, 64); p0 += __shfl_xor(p0, 8, 64);
            p1 += __shfl_xor(p1, 1, 64); p1 += __shfl_xor(p1, 2, 64);
            p1 += __shfl_xor(p1, 4, 64); p1 += __shfl_xor(p1, 8, 64);
            if (r16 == 0) {
                int e = base + rt * 16 + rg + r;
                *reinterpret_cast<float2*>(out + (size_t)2 * e) = make_float2(p0 + b30, p1 + b31);
            }
        }
    }
}

// ---------------- launch ----------------
extern "C" void kernel_launch(void* const* d_in, const int* in_sizes, int n_in,
                              void* d_out, int out_size, void* d_ws, size_t ws_size,
                              hipStream_t stream) {
    const float* x    = (const float*)d_in[0];
    const int*   ei   = (const int*)d_in[1];
    const int*   src  = ei;
    const int*   dst  = ei + NE;
    const float* W1   = (const float*)d_in[2];
    const float* b1   = (const float*)d_in[3];
    const float* g1   = (const float*)d_in[4];
    const float* be1  = (const float*)d_in[5];
    const float* W2   = (const float*)d_in[6];
    const float* b2   = (const float*)d_in[7];
    const float* g2   = (const float*)d_in[8];
    const float* be2  = (const float*)d_in[9];
    const float* W3   = (const float*)d_in[10];
    const float* b3   = (const float*)d_in[11];
    const float* We1  = (const float*)d_in[12];
    const float* bme1 = (const float*)d_in[13];
    const float* We2  = (const float*)d_in[14];
    const float* bme2 = (const float*)d_in[15];
    const float* We3  = (const float*)d_in[16];
    const float* bme3 = (const float*)d_in[17];
    float* out = (float*)d_out;
    char* ws = (char*)d_ws;

    // zero-region (one memset): cnt only
    int*   cnt      = (int*)ws;                           ws += NPAD * 4;
    const size_t zero_bytes = (size_t)NPAD * 4;
    // non-zeroed (partials fully overwritten each run)
    float* part1    = (float*)ws;                         ws += (size_t)BN_PARTS * 512 * 4;
    float* part2    = (float*)ws;                         ws += (size_t)BN_PARTS * 128 * 4;
    float* dsq      = (float*)ws;                         ws += NPAD * 4;
    int*   cursor   = (int*)ws;                           ws += NPAD * 4;
    int*   bsum     = (int*)ws;                           ws += 256 * 4;
    int*   row_start= (int*)ws;                           ws += (NPAD + 16) * 4;
    unsigned short* pk2 = (unsigned short*)ws;            ws += (size_t)NE * 2;
    ws += 64;  // alignment pad
    unsigned short* bufHb = (unsigned short*)ws;          ws += (size_t)NN * 256 * 2;
    unsigned short* bufOb = (unsigned short*)ws;          ws += (size_t)NN * 256 * 2;

    const int nblkE = (NE + 255) / 256;
    const int nblkNode = (NN + 3) / 4;
    const int gy = (NN + 127) / 128;   // 391

    // ---- CSR build + degree terms ----
    hipMemsetAsync(cnt, 0, zero_bytes, stream);
    k_count_int<<<nblkE, 256, 0, stream>>>(dst, cnt);
    k_bsum<<<SCAN_BLOCKS, 256, 0, stream>>>(cnt, bsum);
    k_scan_fin<<<SCAN_BLOCKS, 256, 0, stream>>>(cnt, bsum, row_start, cursor, dsq);
    k_fill<<<nblkE, 256, 0, stream>>>(src, dst, cursor, pk2);

    // ---- layer 1: 256 -> 256 MFMA (fp32 A, bf16+dsq-scaled out), agg, BN partials ----
    k_gemm_mfma<128, false, true, false, false><<<dim3(2, gy), 256, 0, stream>>>(
        x, nullptr, W1, bufHb, NN, 256, 256, nullptr, nullptr, nullptr, dsq);
    k_agg256_b<<<nblkNode, 256, 0, stream>>>(bufHb, row_start, pk2, dsq, b1, bufOb);
    k_bn_stats_b<256><<<BN_PARTS, 256, 0, stream>>>(bufOb, part1);

    // ---- layer 2: A = BN1(bufOb) fused bf16 (partials reduced in-block); 256 -> 64 ----
    k_gemm_mfma<64, true, true, true, false><<<dim3(1, gy), 256, 0, stream>>>(
        nullptr, bufOb, W2, bufHb, NN, 256, 64, part1, g1, be1, dsq);
    k_agg64_b<false><<<nblkNode, 256, 0, stream>>>(bufHb, row_start, pk2, dsq, b2, bufOb);
    k_bn_stats_b<64><<<BN_PARTS, 256, 0, stream>>>(bufOb, part2);

    // ---- layer 3: A = BN2(bufOb) fused; 64 -> 64 MFMA; agg + relu ----
    k_gemm_mfma<64, true, true, true, false><<<dim3(1, gy), 256, 0, stream>>>(
        nullptr, bufOb, W3, bufHb, NN, 64, 64, part2, g2, be2, dsq);
    k_agg64_b<true><<<nblkNode, 256, 0, stream>>>(bufHb, row_start, pk2, dsq, b3, bufOb);

    // ---- layer 4: 64 -> 64 MFMA (bf16 A, same W3/b3, no relu) -> emb in bufOb ----
    k_gemm_mfma<64, false, true, true, false><<<dim3(1, gy), 256, 0, stream>>>(
        nullptr, bufOb, W3, bufHb, NN, 64, 64, nullptr, nullptr, nullptr, dsq);
    k_agg64_b<false><<<nblkNode, 256, 0, stream>>>(bufHb, row_start, pk2, dsq, b3, bufOb);

    // ---- edge MLP: fused A|B gemm (bf16 A) -> AB[NN][128] bf16, then MLP ----
    unsigned short* ABbuf = bufHb;   // NN*128 ushort
    k_gemm_mfma<128, false, false, true, true><<<dim3(1, gy), 256, 0, stream>>>(
        nullptr, bufOb, We1, ABbuf, NN, 64, 128, nullptr, nullptr, nullptr, nullptr);
    k_edge_mlp6<<<NE / EB, EB, 0, stream>>>(ABbuf, src, dst, bme1, We2, bme2, We3, bme3, out);

    (void)in_sizes; (void)n_in; (void)out_size; (void)ws_size;
}